// Round 1
// baseline (146.296 us; speedup 1.0000x reference)
//
#include <hip/hip_runtime.h>

#define NFULL 128
#define NOUT  122
#define NBLK  768

// w-sum ping-pong buffer: [2][5 q][22 rows][WROW]
#define WROW 34
#define WQ   748          // 22*34
#define WB   3740         // 5*WQ
// hw-sum ping-pong buffer: [2][5 q][16 rows][HROW]
#define HROW 34
#define HQ   544          // 16*34
#define HB   2720         // 5*HQ

__device__ __forceinline__ void phaseA_task(const float* __restrict__ px,
                                            const float* __restrict__ py,
                                            float* __restrict__ wp)
{
    float xs[8], ys[8];
#pragma unroll
    for (int k = 0; k < 4; ++k) {
        float2 tx = *(const float2*)(px + 2 * k);
        float2 ty = *(const float2*)(py + 2 * k);
        xs[2 * k] = tx.x; xs[2 * k + 1] = tx.y;
        ys[2 * k] = ty.x; ys[2 * k + 1] = ty.y;
    }
    float sx = 0.f, sy = 0.f, sxx = 0.f, syy = 0.f, sxy = 0.f;
#pragma unroll
    for (int k = 0; k < 7; ++k) {
        sx += xs[k]; sy += ys[k];
        sxx = fmaf(xs[k], xs[k], sxx);
        syy = fmaf(ys[k], ys[k], syy);
        sxy = fmaf(xs[k], ys[k], sxy);
    }
    float tx2 = sx - xs[0] + xs[7];
    float ty2 = sy - ys[0] + ys[7];
    float txx = sxx - xs[0] * xs[0] + xs[7] * xs[7];
    float tyy = syy - ys[0] * ys[0] + ys[7] * ys[7];
    float txy = sxy - xs[0] * ys[0] + xs[7] * ys[7];
    *(float2*)(wp + 0 * WQ) = make_float2(sx,  tx2);
    *(float2*)(wp + 1 * WQ) = make_float2(sy,  ty2);
    *(float2*)(wp + 2 * WQ) = make_float2(sxx, txx);
    *(float2*)(wp + 3 * WQ) = make_float2(syy, tyy);
    *(float2*)(wp + 4 * WQ) = make_float2(sxy, txy);
}

__global__ __launch_bounds__(256, 3)
void ssim3d_kernel(const float* __restrict__ X, const float* __restrict__ Y,
                   const float* __restrict__ DR, double* __restrict__ ws,
                   float* __restrict__ out, int mode)
{
    __shared__ __align__(16) float wbuf[2 * WB];   // 29920 B
    __shared__ __align__(16) float hbuf[2 * HB];   // 21760 B
    __shared__ float  redf[4];
    __shared__ double redd[4];
    __shared__ int lastFlag;

    const int tid = threadIdx.x;
    int bi = blockIdx.x;
    const int bb = bi & 3;  bi >>= 2;   // batch
    const int ht = bi & 7;  bi >>= 3;   // 8 h-tiles of 16
    const int wt = bi & 3;  bi >>= 2;   // 4 w-tiles (0:0-31,1:32-63,2:64-89,3:90-121)
    const int dc = bi;                  // 6 d-chunks

    const int h0 = ht << 4;
    const int w0 = (wt == 3) ? 90 : (wt << 5);
    const int w_hi = (wt == 3) ? 122 : ((wt == 2) ? 90 : (w0 + 32));
    const int csize = (dc < 2) ? 21 : 20;
    const int d0 = (dc < 2) ? dc * 21 : 42 + (dc - 2) * 20;
    const int nsl = csize + 6;          // input slices d0 .. d0+nsl-1 (<=127)

    // SSIM constants, scaled by 343^2 (ratio-invariant)
    const float dr = DR[bb];
    const float c1s = (0.01f * dr) * (0.01f * dr) * 117649.0f;
    const float c2s = (0.03f * dr) * (0.03f * dr) * 117649.0f;
    const float tni = 1.0f / 343.0f;
    const float kkA = 2.0f * 117649.0f / 342.0f;   // A2 coeff
    const float kkB = 117649.0f / 342.0f;          // B2 coeff

    // ---- phase A mapping: base rows 0..15 on all threads ----
    const int sA  = tid & 15;
    const int rA0 = tid >> 4;
    int grA0 = h0 + rA0; if (grA0 > NFULL - 1) grA0 = NFULL - 1;
    const int coffA = w0 + 2 * sA;
    // extra rows 16..21 (96 tasks) on tids 192..255 (wave 3)
    const int eA = tid - 192;
    int rA1 = 0, cA1 = 0, grA1 = 0, rA2 = 0, cA2 = 0, grA2 = 0;
    if (eA >= 0) {
        rA1 = 16 + (eA >> 4); cA1 = eA & 15;
        grA1 = h0 + rA1; if (grA1 > NFULL - 1) grA1 = NFULL - 1;
        if (eA < 32) {
            const int t = eA + 64;
            rA2 = 16 + (t >> 4); cA2 = t & 15;
            grA2 = h0 + rA2; if (grA2 > NFULL - 1) grA2 = NFULL - 1;
        }
    }

    // ---- phase B mapping: 160 tasks (5q x 32 cols) on tids 0..159 ----
    const int bq = tid >> 5;            // 0..4 when tid<160
    const int bc = tid & 31;

    // ---- phase C mapping ----
    const int sC = tid & 15, hC = tid >> 4;
    const int gh  = h0 + hC;
    const int gw0 = w0 + 2 * sC;
    const bool vh = (gh < NOUT);
    const bool vld0 = vh && (gw0 < w_hi);
    const bool vld1 = vh && (gw0 + 1 < w_hi);

    const size_t planeStride = (size_t)NFULL * NFULL;
    const size_t bbase = (size_t)bb * NFULL * planeStride;

    float2 ring[7][5];
    float2 run[5];
#pragma unroll
    for (int k = 0; k < 7; ++k)
#pragma unroll
        for (int q = 0; q < 5; ++q) ring[k][q] = make_float2(0.f, 0.f);
#pragma unroll
    for (int q = 0; q < 5; ++q) run[q] = make_float2(0.f, 0.f);
    float acc = 0.0f;

    // pipeline: A(s) -> wbuf[s&1];  B(s-1): wbuf[(s-1)&1] -> hbuf[(s-1)&1];
    //           C(s-2): hbuf[s&1] -> ring/run/SSIM.  One barrier per slice.
    for (int base = 0; base <= nsl + 1; base += 7) {
#pragma unroll
        for (int u = 0; u < 7; ++u) {
            const int s = base + u;     // uniform across block
            if (s <= nsl + 1) {
                // ---- A(s): global -> w-sums ----
                if (s < nsl) {
                    float* dst = wbuf + (size_t)((s & 1) * WB);
                    const int dIn = d0 + s;
                    const float* Xp = X + bbase + (size_t)dIn * planeStride;
                    const float* Yp = Y + bbase + (size_t)dIn * planeStride;
                    phaseA_task(Xp + grA0 * NFULL + coffA, Yp + grA0 * NFULL + coffA,
                                dst + rA0 * WROW + 2 * sA);
                    if (eA >= 0) {
                        const int co1 = w0 + 2 * cA1;
                        phaseA_task(Xp + grA1 * NFULL + co1, Yp + grA1 * NFULL + co1,
                                    dst + rA1 * WROW + 2 * cA1);
                        if (eA < 32) {
                            const int co2 = w0 + 2 * cA2;
                            phaseA_task(Xp + grA2 * NFULL + co2, Yp + grA2 * NFULL + co2,
                                        dst + rA2 * WROW + 2 * cA2);
                        }
                    }
                }
                // ---- B(s-1): sliding 7-window along h, w-sums -> hw-sums ----
                if (s >= 1 && tid < 160) {
                    const float* src = wbuf + (size_t)(((s - 1) & 1) * WB) + bq * WQ + bc;
                    float* dst = hbuf + (size_t)(((s - 1) & 1) * HB) + bq * HQ + bc;
                    float win = src[0] + src[WROW] + src[2 * WROW] + src[3 * WROW]
                              + src[4 * WROW] + src[5 * WROW];
#pragma unroll
                    for (int h = 0; h < 16; ++h) {
                        win += src[(h + 6) * WROW];
                        dst[h * HROW] = win;
                        win -= src[h * WROW];
                    }
                }
                // ---- C(s-2): hw-sums -> d-ring -> SSIM ----
                if (s >= 2) {
                    const float* src = hbuf + (size_t)((s & 1) * HB) + hC * HROW + 2 * sC;
                    const int slot = (u + 5) % 7;   // (s-2)%7, static after unroll
#pragma unroll
                    for (int q = 0; q < 5; ++q) {
                        float2 h2 = *(const float2*)(src + q * HQ);
                        run[q].x += h2.x - ring[slot][q].x;
                        run[q].y += h2.y - ring[slot][q].y;
                        ring[slot][q] = h2;
                    }
                    if (s >= 8) {
#pragma unroll
                        for (int j = 0; j < 2; ++j) {
                            const bool vld = j ? vld1 : vld0;
                            if (vld) {
                                float Sx  = j ? run[0].y : run[0].x;
                                float Sy  = j ? run[1].y : run[1].x;
                                float Sxx = j ? run[2].y : run[2].x;
                                float Syy = j ? run[3].y : run[3].x;
                                float Sxy = j ? run[4].y : run[4].x;
                                float P = Sx * Sy;
                                float Q = fmaf(Sx, Sx, Sy * Sy);
                                float A1 = fmaf(2.f, P, c1s);
                                float A2 = fmaf(kkA, fmaf(-tni, P, Sxy), c2s);
                                float B1 = Q + c1s;
                                float B2 = fmaf(kkB, fmaf(-tni, Q, Sxx + Syy), c2s);
                                float num = A1 * A2;
                                float den = B1 * B2;
                                float r0 = __builtin_amdgcn_rcpf(den);
                                r0 = r0 * fmaf(-den, r0, 2.0f);   // 1 Newton step
                                acc = fmaf(num, r0, acc);
                            }
                        }
                    }
                }
                __syncthreads();
            }
        }
    }

    // ---- reduction: wave shuffle -> LDS -> per-block partial (double) ----
#pragma unroll
    for (int off = 32; off; off >>= 1) acc += __shfl_down(acc, off);
    if ((tid & 63) == 0) redf[tid >> 6] = acc;
    __syncthreads();

    if (mode) {
        if (tid == 0) {
            double t = (double)redf[0] + (double)redf[1] + (double)redf[2] + (double)redf[3];
            ws[blockIdx.x] = t;
            __threadfence();
            unsigned int old = atomicAdd((unsigned int*)(ws + NBLK), 1u);
            lastFlag = (old == NBLK - 1) ? 1 : 0;
        }
        __syncthreads();
        if (lastFlag) {     // last-arriving block does the finalize
            __threadfence();
            double t = 0.0;
            for (int i = tid; i < NBLK; i += 256) t += ws[i];
#pragma unroll
            for (int off = 32; off; off >>= 1) t += __shfl_down(t, off);
            if ((tid & 63) == 0) redd[tid >> 6] = t;
            __syncthreads();
            if (tid == 0)
                out[0] = (float)((redd[0] + redd[1] + redd[2] + redd[3])
                                 * (1.0 / 7263392.0));   // 4 * 122^3
        }
    } else {
        if (tid == 0) {
            double t = (double)redf[0] + (double)redf[1] + (double)redf[2] + (double)redf[3];
            atomicAdd(ws, t);
        }
    }
}

__global__ void ssim3d_finalize(const double* __restrict__ ws, float* __restrict__ out)
{
    out[0] = (float)(ws[0] * (1.0 / 7263392.0));
}

extern "C" void kernel_launch(void* const* d_in, const int* in_sizes, int n_in,
                              void* d_out, int out_size, void* d_ws, size_t ws_size,
                              hipStream_t stream)
{
    const float* X  = (const float*)d_in[0];
    const float* Y  = (const float*)d_in[1];
    const float* DR = (const float*)d_in[2];
    double* ws = (double*)d_ws;

    const int mode = (ws_size >= (size_t)(NBLK + 1) * sizeof(double)) ? 1 : 0;
    if (mode)
        hipMemsetAsync((char*)d_ws + (size_t)NBLK * sizeof(double), 0, sizeof(double), stream);
    else
        hipMemsetAsync(d_ws, 0, sizeof(double), stream);

    ssim3d_kernel<<<NBLK, 256, 0, stream>>>(X, Y, DR, ws, (float*)d_out, mode);
    if (!mode) ssim3d_finalize<<<1, 1, 0, stream>>>(ws, (float*)d_out);
}

// Round 2
// 142.215 us; speedup vs baseline: 1.0287x; 1.0287x over previous
//
#include <hip/hip_runtime.h>

#define NFULL 128
#define NOUT  122
#define NBLK  512
#define NTHR  512

// single-buffer w-sums: [5 q][22 rows][34]
#define WROW 34
#define WQ   748          // 22*34
#define WB   3740         // 5*WQ
// single-buffer hw-sums: [5 q][16 rows][34]
#define HROW 34
#define HQ   544          // 16*34
#define HB   2720         // 5*HQ

__device__ __forceinline__ void phaseA_task(const float* __restrict__ px,
                                            const float* __restrict__ py,
                                            float* __restrict__ wp)
{
    float xs[8], ys[8];
#pragma unroll
    for (int k = 0; k < 4; ++k) {
        float2 tx = *(const float2*)(px + 2 * k);
        float2 ty = *(const float2*)(py + 2 * k);
        xs[2 * k] = tx.x; xs[2 * k + 1] = tx.y;
        ys[2 * k] = ty.x; ys[2 * k + 1] = ty.y;
    }
    float sx = 0.f, sy = 0.f, sxx = 0.f, syy = 0.f, sxy = 0.f;
#pragma unroll
    for (int k = 0; k < 7; ++k) {
        sx += xs[k]; sy += ys[k];
        sxx = fmaf(xs[k], xs[k], sxx);
        syy = fmaf(ys[k], ys[k], syy);
        sxy = fmaf(xs[k], ys[k], sxy);
    }
    float tx2 = sx - xs[0] + xs[7];
    float ty2 = sy - ys[0] + ys[7];
    float txx = sxx - xs[0] * xs[0] + xs[7] * xs[7];
    float tyy = syy - ys[0] * ys[0] + ys[7] * ys[7];
    float txy = sxy - xs[0] * ys[0] + xs[7] * ys[7];
    *(float2*)(wp + 0 * WQ) = make_float2(sx,  tx2);
    *(float2*)(wp + 1 * WQ) = make_float2(sy,  ty2);
    *(float2*)(wp + 2 * WQ) = make_float2(sxx, txx);
    *(float2*)(wp + 3 * WQ) = make_float2(syy, tyy);
    *(float2*)(wp + 4 * WQ) = make_float2(sxy, txy);
}

__global__ __launch_bounds__(NTHR, 4)
void ssim3d_kernel(const float* __restrict__ X, const float* __restrict__ Y,
                   const float* __restrict__ DR, double* __restrict__ ws,
                   float* __restrict__ out, int mode)
{
    __shared__ __align__(16) float wbuf[WB];    // 14960 B
    __shared__ __align__(16) float hbuf[HB];    // 10880 B
    __shared__ float  redf[8];
    __shared__ double redd[8];
    __shared__ int lastFlag;

    const int tid = threadIdx.x;
    int bi = blockIdx.x;
    const int bb = bi & 3;  bi >>= 2;   // batch
    const int ht = bi & 7;  bi >>= 3;   // 8 h-tiles of 16
    const int wt = bi & 3;  bi >>= 2;   // 4 w-tiles (0:0-31,1:32-63,2:64-89,3:90-121)
    const int dc = bi;                  // 4 d-chunks (31,31,30,30 outputs)

    const int h0 = ht << 4;
    const int w0 = (wt == 3) ? 90 : (wt << 5);
    const int w_hi = (wt == 3) ? 122 : ((wt == 2) ? 90 : (w0 + 32));
    const int csize = (dc < 2) ? 31 : 30;
    const int d0 = (dc < 2) ? dc * 31 : 62 + (dc - 2) * 30;
    const int nsl = csize + 6;          // input slices d0 .. d0+nsl-1 (<=127)

    // SSIM constants, scaled by 343^2 (ratio-invariant)
    const float dr = DR[bb];
    const float c1s = (0.01f * dr) * (0.01f * dr) * 117649.0f;
    const float c2s = (0.03f * dr) * (0.03f * dr) * 117649.0f;
    const float tni = 1.0f / 343.0f;
    const float kkA = 2.0f * 117649.0f / 342.0f;   // A2 coeff
    const float kkB = 117649.0f / 342.0f;          // B2 coeff

    // ---- phase A mapping: 352 tasks (22 rows x 16 col-pairs) on tids 160..511
    const int aid = tid - 160;
    const int rA  = aid >> 4;           // 0..21  (valid when aid>=0)
    const int sA  = aid & 15;
    int grA = h0 + rA; if (grA > NFULL - 1) grA = NFULL - 1;
    const int coffA = w0 + 2 * sA;

    // ---- phase B mapping: 160 tasks (5 q x 32 cols) on tids 0..159
    const int bq = tid >> 5;            // 0..4 when tid<160
    const int bc = tid & 31;

    // ---- phase C mapping: 512 tasks (16 h x 32 w), one column per thread
    const int sC = tid & 31, hC = tid >> 5;
    const int gh = h0 + hC;
    const int gw = w0 + sC;
    const bool vld = (gh < NOUT) && (gw < w_hi);

    const size_t planeStride = (size_t)NFULL * NFULL;
    const size_t bbase = (size_t)bb * NFULL * planeStride;

    float ring[7][5];
    float run[5];
#pragma unroll
    for (int k = 0; k < 7; ++k)
#pragma unroll
        for (int q = 0; q < 5; ++q) ring[k][q] = 0.f;
#pragma unroll
    for (int q = 0; q < 5; ++q) run[q] = 0.f;
    float acc = 0.0f;

    // Per slice s:  sub1: A(s)->wbuf  ||  C(s-1)<-hbuf ;  barrier;
    //               sub2: B(s): wbuf->hbuf ;              barrier.
    // Single-buffered wbuf/hbuf are safe: every producer/consumer pair is
    // separated by exactly one barrier.
    for (int base = 0; base <= nsl; base += 7) {
#pragma unroll
        for (int u = 0; u < 7; ++u) {
            const int s = base + u;     // uniform across block
            if (s <= nsl) {
                // ---- sub-phase 1 ----
                if (s < nsl && aid >= 0) {
                    const int dIn = d0 + s;
                    const float* Xp = X + bbase + (size_t)dIn * planeStride;
                    const float* Yp = Y + bbase + (size_t)dIn * planeStride;
                    phaseA_task(Xp + grA * NFULL + coffA, Yp + grA * NFULL + coffA,
                                wbuf + rA * WROW + 2 * sA);
                }
                if (s >= 1) {
                    const float* src = hbuf + hC * HROW + sC;
                    const int slot = (u + 6) % 7;   // (s-1)%7, static after unroll
#pragma unroll
                    for (int q = 0; q < 5; ++q) {
                        float v = src[q * HQ];
                        run[q] += v - ring[slot][q];
                        ring[slot][q] = v;
                    }
                    if (s >= 7 && vld) {
                        float Sx  = run[0];
                        float Sy  = run[1];
                        float Sxx = run[2];
                        float Syy = run[3];
                        float Sxy = run[4];
                        float P = Sx * Sy;
                        float Q = fmaf(Sx, Sx, Sy * Sy);
                        float A1 = fmaf(2.f, P, c1s);
                        float A2 = fmaf(kkA, fmaf(-tni, P, Sxy), c2s);
                        float B1 = Q + c1s;
                        float B2 = fmaf(kkB, fmaf(-tni, Q, Sxx + Syy), c2s);
                        float num = A1 * A2;
                        float den = B1 * B2;
                        float r0 = __builtin_amdgcn_rcpf(den);
                        r0 = r0 * fmaf(-den, r0, 2.0f);   // 1 Newton step
                        acc = fmaf(num, r0, acc);
                    }
                }
                __syncthreads();
                // ---- sub-phase 2: sliding 7-window along h ----
                if (s < nsl && tid < 160) {
                    const float* srcw = wbuf + bq * WQ + bc;
                    float* dsth = hbuf + bq * HQ + bc;
                    float win = srcw[0] + srcw[WROW] + srcw[2 * WROW]
                              + srcw[3 * WROW] + srcw[4 * WROW] + srcw[5 * WROW];
#pragma unroll
                    for (int h = 0; h < 16; ++h) {
                        win += srcw[(h + 6) * WROW];
                        dsth[h * HROW] = win;
                        win -= srcw[h * WROW];
                    }
                }
                __syncthreads();
            }
        }
    }

    // ---- reduction: wave shuffle -> LDS -> per-block partial (double) ----
#pragma unroll
    for (int off = 32; off; off >>= 1) acc += __shfl_down(acc, off);
    if ((tid & 63) == 0) redf[tid >> 6] = acc;
    __syncthreads();

    if (mode) {
        if (tid == 0) {
            double t = 0.0;
#pragma unroll
            for (int i = 0; i < 8; ++i) t += (double)redf[i];
            ws[blockIdx.x] = t;
            __threadfence();
            unsigned int old = atomicAdd((unsigned int*)(ws + NBLK), 1u);
            lastFlag = (old == NBLK - 1) ? 1 : 0;
        }
        __syncthreads();
        if (lastFlag) {     // last-arriving block does the finalize
            __threadfence();
            double t = 0.0;
            for (int i = tid; i < NBLK; i += NTHR) t += ws[i];
#pragma unroll
            for (int off = 32; off; off >>= 1) t += __shfl_down(t, off);
            if ((tid & 63) == 0) redd[tid >> 6] = t;
            __syncthreads();
            if (tid == 0) {
                double r = 0.0;
#pragma unroll
                for (int i = 0; i < 8; ++i) r += redd[i];
                out[0] = (float)(r * (1.0 / 7263392.0));   // 4 * 122^3
            }
        }
    } else {
        if (tid == 0) {
            double t = 0.0;
#pragma unroll
            for (int i = 0; i < 8; ++i) t += (double)redf[i];
            atomicAdd(ws, t);
        }
    }
}

__global__ void ssim3d_finalize(const double* __restrict__ ws, float* __restrict__ out)
{
    out[0] = (float)(ws[0] * (1.0 / 7263392.0));
}

extern "C" void kernel_launch(void* const* d_in, const int* in_sizes, int n_in,
                              void* d_out, int out_size, void* d_ws, size_t ws_size,
                              hipStream_t stream)
{
    const float* X  = (const float*)d_in[0];
    const float* Y  = (const float*)d_in[1];
    const float* DR = (const float*)d_in[2];
    double* ws = (double*)d_ws;

    const int mode = (ws_size >= (size_t)(NBLK + 1) * sizeof(double)) ? 1 : 0;
    if (mode)
        hipMemsetAsync((char*)d_ws + (size_t)NBLK * sizeof(double), 0, sizeof(double), stream);
    else
        hipMemsetAsync(d_ws, 0, sizeof(double), stream);

    ssim3d_kernel<<<NBLK, NTHR, 0, stream>>>(X, Y, DR, ws, (float*)d_out, mode);
    if (!mode) ssim3d_finalize<<<1, 1, 0, stream>>>(ws, (float*)d_out);
}